// Round 1
// baseline (250.177 us; speedup 1.0000x reference)
//
#include <hip/hip_runtime.h>

// Involution2d: x[4,256,64,64], w_kernel[784,256], b_kernel[784] -> out[4,256,64,64]
// kern[b,k,h,w] = sum_c x[b,c,h,w]*w[k,c] + bias[k]   (k = g*49 + kh*7+kw)
// out[b, g*16+cg, h, w] = sum_{kh,kw} x_pad[b, g*16+cg, h+kh-3, w+kw-3] * kern[b, g*49+kh*7+kw, h, w]

#define B_   4
#define C_   256
#define H_   64
#define W_   64
#define G_   16
#define CG_  16      // channels per group
#define KS_  7
#define PD_  3
#define KK_  49
#define TS_  16      // pixel tile: 16x16
#define HALO 22      // TS + KS - 1
#define HROW 24      // padded LDS row (2-way bank aliasing only => free)
#define HWSZ (H_*W_)

__global__ __launch_bounds__(256, 4)
void involution_fused(const float* __restrict__ x,
                      const float* __restrict__ wk,
                      const float* __restrict__ bk,
                      float* __restrict__ out) {
    // phase 1 uses first CG_*256 floats (16KB); phase 2 uses all (33.8KB)
    __shared__ float smem[CG_ * HALO * HROW];   // 16*22*24 = 8448 floats

    const int bid  = blockIdx.x;
    const int tile = bid & 15;          // 16 tiles per (b,g) image
    const int g    = (bid >> 4) & 15;
    const int b    = bid >> 8;
    const int ty   = tile >> 2, tx = tile & 3;
    const int gy0  = ty * TS_, gx0 = tx * TS_;

    const int tid = threadIdx.x;
    const int py  = tid >> 4, px = tid & 15;
    const int gy  = gy0 + py, gx = gx0 + px;

    const size_t xb = (size_t)b * C_ * HWSZ;

    // per-thread dynamic kernel accumulators (this pixel, this group): 49 VGPRs
    float kern[KK_];
    #pragma unroll
    for (int k = 0; k < KK_; ++k) kern[k] = bk[g * KK_ + k];

    // ---------------- Phase 1: kern = W @ x[:, pixel] + b ----------------
    for (int cc = 0; cc < C_; cc += 16) {
        // stage 16 channels x (16x16 tile) into LDS, float4 loads
        #pragma unroll
        for (int r = 0; r < 4; ++r) {
            int e    = r * 256 + tid;      // float4 index, 0..1023
            int ch   = e >> 6;             // 64 float4 per channel tile
            int rest = e & 63;
            int ly   = rest >> 2;
            int lx4  = (rest & 3) << 2;
            const float* src = x + xb + (size_t)(cc + ch) * HWSZ
                               + (size_t)(gy0 + ly) * W_ + gx0 + lx4;
            float4 v = *reinterpret_cast<const float4*>(src);
            *reinterpret_cast<float4*>(&smem[ch * 256 + ly * 16 + lx4]) = v;
        }
        __syncthreads();

        float xv[16];
        #pragma unroll
        for (int ch = 0; ch < 16; ++ch) xv[ch] = smem[ch * 256 + tid];

        const float* wbase = wk + (size_t)(g * KK_) * C_ + cc;  // uniform -> s_load
        #pragma unroll
        for (int k = 0; k < KK_; ++k) {
            #pragma unroll
            for (int ch = 0; ch < 16; ++ch) {
                kern[k] = fmaf(xv[ch], wbase[k * C_ + ch], kern[k]);
            }
        }
        __syncthreads();   // protect LDS before next chunk overwrite
    }

    // ---------------- Phase 2: involution over 7x7 neighborhood ----------------
    // load halo tile for this group's 16 channels: 16 x 22 x 22 (zero-padded)
    for (int idx = tid; idx < CG_ * HALO * HALO; idx += 256) {
        int ch = idx / (HALO * HALO);
        int r  = idx - ch * (HALO * HALO);
        int hy = r / HALO;
        int hx = r - hy * HALO;
        int sy = gy0 + hy - PD_;
        int sx = gx0 + hx - PD_;
        float v = 0.0f;
        if (sy >= 0 && sy < H_ && sx >= 0 && sx < W_)
            v = x[xb + (size_t)(g * CG_ + ch) * HWSZ + (size_t)sy * W_ + sx];
        smem[ch * (HALO * HROW) + hy * HROW + hx] = v;
    }
    __syncthreads();

    const size_t ob = xb + (size_t)(g * CG_) * HWSZ;
    #pragma unroll 1
    for (int cg = 0; cg < CG_; ++cg) {
        const float* xs = &smem[cg * (HALO * HROW) + py * HROW + px];
        float acc = 0.0f;
        #pragma unroll
        for (int kh = 0; kh < KS_; ++kh) {
            #pragma unroll
            for (int kw = 0; kw < KS_; ++kw) {
                acc = fmaf(xs[kh * HROW + kw], kern[kh * KS_ + kw], acc);
            }
        }
        out[ob + (size_t)cg * HWSZ + (size_t)gy * W_ + gx] = acc;
    }
}

extern "C" void kernel_launch(void* const* d_in, const int* in_sizes, int n_in,
                              void* d_out, int out_size, void* d_ws, size_t ws_size,
                              hipStream_t stream) {
    const float* x  = (const float*)d_in[0];
    const float* wk = (const float*)d_in[1];
    const float* bk = (const float*)d_in[2];
    float* out = (float*)d_out;
    // grid: 4 batches * 16 groups * 16 tiles = 1024 blocks
    involution_fused<<<dim3(B_ * G_ * 16), dim3(256), 0, stream>>>(x, wk, bk, out);
}

// Round 2
// 149.659 us; speedup vs baseline: 1.6716x; 1.6716x over previous
//
#include <hip/hip_runtime.h>

// Involution2d via bf16 MFMA for the per-pixel kernel GEMM.
// x[4,256,64,64], w[784,256], b[784] -> out[4,256,64,64]
// Per block (b, g, 16x16 pixel tile):
//   Phase 1 (MFMA): kern[49 x 256px] = W_g[49 x 256ch] @ X[256ch x 256px] + bias
//   Phase 2 (VALU): out[cg,p] = sum_{7x7} halo[cg, p+off] * kern[koff, p]

#define B_   4
#define C_   256
#define H_   64
#define W_   64
#define G_   16
#define CG_  16
#define KS_  7
#define PD_  3
#define KK_  49
#define TS_  16
#define HALO 22
#define HROW 24
#define HWSZ (H_*W_)

#define SK   264                       // kern_lds row stride (bf16 elems), 132 dwords = 4 mod 32
#define XS   40                        // xstage row stride (bf16 elems), 20 dwords = banks {0,4,..,28}
#define KERN_BYTES (KK_*SK*2)          // 25872
#define XSTAGE_OFF KERN_BYTES          // xstage and halo overlap (disjoint lifetimes)
#define HALO_OFF   KERN_BYTES
#define SMEM_BYTES (KERN_BYTES + CG_*HALO*HROW*4)   // 25872 + 33792 = 59664 < 64K

typedef __attribute__((ext_vector_type(8))) short bf16x8;
typedef __attribute__((ext_vector_type(4))) float f32x4;

__device__ inline unsigned f2bf(float f) {           // RNE fp32->bf16 (low 16 of result)
    unsigned u = __float_as_uint(f);
    u += 0x7FFF + ((u >> 16) & 1);
    return u >> 16;
}
__device__ inline float bf2f(unsigned short s) {
    return __uint_as_float(((unsigned)s) << 16);
}

__global__ __launch_bounds__(256, 2)
void involution_mfma(const float* __restrict__ x,
                     const float* __restrict__ wk,
                     const float* __restrict__ bk,
                     float* __restrict__ out) {
    __shared__ char smem[SMEM_BYTES];
    unsigned short* kern_lds = (unsigned short*)smem;                 // [49][264] bf16
    unsigned short* xstage   = (unsigned short*)(smem + XSTAGE_OFF);  // [256 px][40] bf16
    float*          halo     = (float*)(smem + HALO_OFF);             // [16][22][24] f32

    const int bid  = blockIdx.x;
    const int tile = bid & 15;
    const int g    = (bid >> 4) & 15;
    const int b    = bid >> 8;
    const int gy0  = (tile >> 2) * TS_;
    const int gx0  = (tile & 3) * TS_;

    const int tid  = threadIdx.x;
    const int wv   = tid >> 6;         // wave id: owns m-rows 16wv..16wv+15
    const int lane = tid & 63;
    const int ln15 = lane & 15;
    const int quad = lane >> 4;

    const int py = tid >> 4, px = tid & 15;   // this thread's pixel (linear p = tid)
    const int gy = gy0 + py, gx = gx0 + px;
    const size_t xb = (size_t)b * C_ * HWSZ;
    const int pixoff = gy * W_ + gx;

    f32x4 acc[16];
    #pragma unroll
    for (int nt = 0; nt < 16; ++nt) acc[nt] = (f32x4){0.f, 0.f, 0.f, 0.f};

    // A-operand row for this lane: A[m=lane&15][k=quad*8+j] (m120-verified layout)
    int rowg = 16*wv + ln15; if (rowg > KK_-1) rowg = KK_-1;   // clamp: rows 49..63 are dummies
    const float* wrow = wk + (size_t)(g*KK_ + rowg) * C_;

    // ---------------- Phase 1: K-loop over 8 chunks of 32 channels ----------------
    for (int cc = 0; cc < C_; cc += 32) {
        __syncthreads();   // previous iteration's B-frag readers done with xstage
        // stage X chunk transposed: thread p writes its pixel's 32 ch as bf16 row
        unsigned upk[16];
        #pragma unroll
        for (int c = 0; c < 32; c += 2) {
            float a0 = x[xb + (size_t)(cc + c    ) * HWSZ + pixoff];
            float a1 = x[xb + (size_t)(cc + c + 1) * HWSZ + pixoff];
            upk[c >> 1] = f2bf(a0) | (f2bf(a1) << 16);
        }
        unsigned* xrow = (unsigned*)&xstage[tid * XS];   // 80B row base: 16B aligned
        #pragma unroll
        for (int q = 0; q < 4; ++q)
            ((uint4*)xrow)[q] = make_uint4(upk[4*q], upk[4*q+1], upk[4*q+2], upk[4*q+3]);
        __syncthreads();

        // A-frag: 8 consecutive w channels for this lane's m-row (global, L1/L2-cached)
        const float4 w0 = *(const float4*)(wrow + cc + quad*8);
        const float4 w1 = *(const float4*)(wrow + cc + quad*8 + 4);
        union { bf16x8 v; unsigned u[4]; } af;
        af.u[0] = f2bf(w0.x) | (f2bf(w0.y) << 16);
        af.u[1] = f2bf(w0.z) | (f2bf(w0.w) << 16);
        af.u[2] = f2bf(w1.x) | (f2bf(w1.y) << 16);
        af.u[3] = f2bf(w1.z) | (f2bf(w1.w) << 16);

        // 16 n-tiles of 16 pixels; B[k=quad*8+j][n=lane&15] via one ds_read_b128
        #pragma unroll
        for (int nt = 0; nt < 16; ++nt) {
            bf16x8 bf = *(const bf16x8*)&xstage[(nt*16 + ln15) * XS + quad*8];
            acc[nt] = __builtin_amdgcn_mfma_f32_16x16x32_bf16(af.v, bf, acc[nt], 0, 0, 0);
        }
    }

    // ---------------- Epilogue: bias + bf16 kern into LDS ----------------
    float biasr[4];
    #pragma unroll
    for (int r = 0; r < 4; ++r) {
        int m = 16*wv + quad*4 + r; if (m > KK_-1) m = KK_-1;
        biasr[r] = bk[g*KK_ + m];
    }
    #pragma unroll
    for (int nt = 0; nt < 16; ++nt) {
        #pragma unroll
        for (int r = 0; r < 4; ++r) {
            int m = 16*wv + quad*4 + r;               // D[m=quad*4+reg][n=lane&15]
            if (m < KK_)
                kern_lds[m*SK + nt*16 + ln15] = (unsigned short)f2bf(acc[nt][r] + biasr[r]);
        }
    }
    __syncthreads();   // kern_lds complete; all waves done with xstage

    // ---------------- Phase 2: stage fp32 halo (overlaps xstage region) ----------------
    for (int idx = tid; idx < CG_*HALO*HALO; idx += 256) {
        int ch = idx / (HALO*HALO);
        int r  = idx - ch*(HALO*HALO);
        int hy = r / HALO;
        int hx = r - hy*HALO;
        int sy = gy0 + hy - PD_;
        int sx = gx0 + hx - PD_;
        float v = 0.f;
        if (sy >= 0 && sy < H_ && sx >= 0 && sx < W_)
            v = x[xb + (size_t)(g*CG_ + ch)*HWSZ + (size_t)sy*W_ + sx];
        halo[ch*(HALO*HROW) + hy*HROW + hx] = v;
    }

    // my pixel's 49 kernel values (kern_lds region is stable)
    float kernv[KK_];
    #pragma unroll
    for (int k = 0; k < KK_; ++k) kernv[k] = bf2f(kern_lds[k*SK + tid]);

    __syncthreads();

    const size_t ob = xb + (size_t)(g*CG_) * HWSZ;
    #pragma unroll 1
    for (int cg = 0; cg < CG_; ++cg) {
        const float* xs = &halo[cg*(HALO*HROW) + py*HROW + px];
        float a2 = 0.f;
        #pragma unroll
        for (int kh = 0; kh < KS_; ++kh) {
            #pragma unroll
            for (int kw = 0; kw < KS_; ++kw) {
                a2 = fmaf(xs[kh*HROW + kw], kernv[kh*KS_ + kw], a2);
            }
        }
        out[ob + (size_t)cg*HWSZ + (size_t)gy*W_ + gx] = a2;
    }
}

extern "C" void kernel_launch(void* const* d_in, const int* in_sizes, int n_in,
                              void* d_out, int out_size, void* d_ws, size_t ws_size,
                              hipStream_t stream) {
    const float* x  = (const float*)d_in[0];
    const float* wk = (const float*)d_in[1];
    const float* bk = (const float*)d_in[2];
    float* o = (float*)d_out;
    involution_mfma<<<dim3(B_ * G_ * 16), dim3(256), 0, stream>>>(x, wk, bk, o);
}

// Round 3
// 146.234 us; speedup vs baseline: 1.7108x; 1.0234x over previous
//
#include <hip/hip_runtime.h>

// Involution2d via bf16 MFMA for the per-pixel kernel GEMM.
// x[4,256,64,64], w[784,256], b[784] -> out[4,256,64,64]
// Per block (b, g, 16x16 pixel tile):
//   Phase 1 (MFMA): kern[49 x 256px] = W_g[49 x 256ch] @ X[256ch x 256px] + bias
//   Phase 2 (VALU): out[cg,p] = sum_{7x7} halo[cg, p+off] * kern[koff, p]
// R2: 3 blocks/CU (LDS 46.4KB), x-chunk register prefetch, halo in 2 batches.

#define B_   4
#define C_   256
#define H_   64
#define W_   64
#define G_   16
#define CG_  16
#define KS_  7
#define PD_  3
#define KK_  49
#define TS_  16
#define HALO 22
#define HROW 24
#define HWSZ (H_*W_)
#define HB_  8                         // halo channels per batch
#define NHB  (CG_/HB_)                 // 2 batches

#define SK   264                       // kern_lds row stride (bf16), 132 dwords
#define XS   40                        // xstage row stride (bf16), 20 dwords
#define KERN_BYTES (KK_*SK*2)          // 25872
#define UNION_BYTES (256*XS*2)         // xstage 20480 >= halo batch 16896
#define SMEM_BYTES (KERN_BYTES + UNION_BYTES)   // 46352 -> 3 blocks/CU

typedef __attribute__((ext_vector_type(8))) short bf16x8;
typedef __attribute__((ext_vector_type(4))) float f32x4;

__device__ inline unsigned f2bf(float f) {           // RNE fp32->bf16
    unsigned u = __float_as_uint(f);
    u += 0x7FFF + ((u >> 16) & 1);
    return u >> 16;
}
__device__ inline float bf2f(unsigned short s) {
    return __uint_as_float(((unsigned)s) << 16);
}

__global__ __launch_bounds__(256, 3)
void involution_mfma(const float* __restrict__ x,
                     const float* __restrict__ wk,
                     const float* __restrict__ bk,
                     float* __restrict__ out) {
    __shared__ char smem[SMEM_BYTES];
    unsigned short* kern_lds = (unsigned short*)smem;                 // [49][264] bf16
    unsigned short* xstage   = (unsigned short*)(smem + KERN_BYTES);  // [256 px][40] bf16
    float*          halo     = (float*)(smem + KERN_BYTES);           // [8][22][24] f32 (batched)

    const int bid  = blockIdx.x;
    const int tile = bid & 15;
    const int g    = (bid >> 4) & 15;
    const int b    = bid >> 8;
    const int gy0  = (tile >> 2) * TS_;
    const int gx0  = (tile & 3) * TS_;

    const int tid  = threadIdx.x;
    const int wv   = tid >> 6;
    const int lane = tid & 63;
    const int ln15 = lane & 15;
    const int quad = lane >> 4;

    const int py = tid >> 4, px = tid & 15;
    const int gy = gy0 + py, gx = gx0 + px;
    const size_t xb = (size_t)b * C_ * HWSZ;
    const int pixoff = gy * W_ + gx;

    f32x4 acc[16];
    #pragma unroll
    for (int nt = 0; nt < 16; ++nt) acc[nt] = (f32x4){0.f, 0.f, 0.f, 0.f};

    // A row for this lane: A[m=lane&15][k=quad*8+j]
    int rowg = 16*wv + ln15; if (rowg > KK_-1) rowg = KK_-1;
    const float* wrow = wk + (size_t)(g*KK_ + rowg) * C_;

    // preload chunk 0 into registers
    float xv[32];
    #pragma unroll
    for (int c = 0; c < 32; ++c) xv[c] = x[xb + (size_t)c * HWSZ + pixoff];

    // ---------------- Phase 1: 8 chunks of 32 channels, reg-prefetched ----------------
    for (int cc = 0; cc < C_; cc += 32) {
        // pack current chunk to bf16 and write transposed row [px][ch]
        unsigned upk[16];
        #pragma unroll
        for (int c = 0; c < 32; c += 2)
            upk[c >> 1] = f2bf(xv[c]) | (f2bf(xv[c + 1]) << 16);
        unsigned* xrow = (unsigned*)&xstage[tid * XS];
        #pragma unroll
        for (int q = 0; q < 4; ++q)
            ((uint4*)xrow)[q] = make_uint4(upk[4*q], upk[4*q+1], upk[4*q+2], upk[4*q+3]);
        __syncthreads();

        // prefetch next chunk (in flight during ds_read+MFMA below)
        if (cc + 32 < C_) {
            #pragma unroll
            for (int c = 0; c < 32; ++c)
                xv[c] = x[xb + (size_t)(cc + 32 + c) * HWSZ + pixoff];
        }

        // A-frag: 8 w channels for this lane's m-row (L1/L2-cached)
        const float4 w0 = *(const float4*)(wrow + cc + quad*8);
        const float4 w1 = *(const float4*)(wrow + cc + quad*8 + 4);
        union { bf16x8 v; unsigned u[4]; } af;
        af.u[0] = f2bf(w0.x) | (f2bf(w0.y) << 16);
        af.u[1] = f2bf(w0.z) | (f2bf(w0.w) << 16);
        af.u[2] = f2bf(w1.x) | (f2bf(w1.y) << 16);
        af.u[3] = f2bf(w1.z) | (f2bf(w1.w) << 16);

        #pragma unroll
        for (int nt = 0; nt < 16; ++nt) {
            bf16x8 bf = *(const bf16x8*)&xstage[(nt*16 + ln15) * XS + quad*8];
            acc[nt] = __builtin_amdgcn_mfma_f32_16x16x32_bf16(af.v, bf, acc[nt], 0, 0, 0);
        }
        __syncthreads();   // readers done before next overwrite
    }

    // ---------------- Epilogue: bias + bf16 kern into LDS ----------------
    float biasr[4];
    #pragma unroll
    for (int r = 0; r < 4; ++r) {
        int m = 16*wv + quad*4 + r; if (m > KK_-1) m = KK_-1;
        biasr[r] = bk[g*KK_ + m];
    }
    #pragma unroll
    for (int nt = 0; nt < 16; ++nt) {
        #pragma unroll
        for (int r = 0; r < 4; ++r) {
            int m = 16*wv + quad*4 + r;               // D[m=quad*4+reg][n=lane&15]
            if (m < KK_)
                kern_lds[m*SK + nt*16 + ln15] = (unsigned short)f2bf(acc[nt][r] + biasr[r]);
        }
    }
    __syncthreads();   // kern_lds complete; xstage free for halo

    // my pixel's 49 kernel values
    float kernv[KK_];
    #pragma unroll
    for (int k = 0; k < KK_; ++k) kernv[k] = bf2f(kern_lds[k*SK + tid]);

    // ---------------- Phase 2: involution, halo staged in 2 batches of 8 ch ----------------
    const size_t ob = xb + (size_t)(g*CG_) * HWSZ;
    #pragma unroll 1
    for (int hb = 0; hb < NHB; ++hb) {
        if (hb) __syncthreads();   // previous batch consumers done
        for (int idx = tid; idx < HB_*HALO*HALO; idx += 256) {
            int ch = idx / (HALO*HALO);
            int r  = idx - ch*(HALO*HALO);
            int hy = r / HALO;
            int hx = r - hy*HALO;
            int sy = gy0 + hy - PD_;
            int sx = gx0 + hx - PD_;
            float v = 0.f;
            if (sy >= 0 && sy < H_ && sx >= 0 && sx < W_)
                v = x[xb + (size_t)(g*CG_ + hb*HB_ + ch)*HWSZ + (size_t)sy*W_ + sx];
            halo[ch*(HALO*HROW) + hy*HROW + hx] = v;
        }
        __syncthreads();

        #pragma unroll 1
        for (int c = 0; c < HB_; ++c) {
            const float* xs = &halo[c*(HALO*HROW) + py*HROW + px];
            float a2 = 0.f;
            #pragma unroll
            for (int kh = 0; kh < KS_; ++kh) {
                #pragma unroll
                for (int kw = 0; kw < KS_; ++kw) {
                    a2 = fmaf(xs[kh*HROW + kw], kernv[kh*KS_ + kw], a2);
                }
            }
            out[ob + (size_t)(hb*HB_ + c)*HWSZ + (size_t)gy*W_ + gx] = a2;
        }
    }
}

extern "C" void kernel_launch(void* const* d_in, const int* in_sizes, int n_in,
                              void* d_out, int out_size, void* d_ws, size_t ws_size,
                              hipStream_t stream) {
    const float* x  = (const float*)d_in[0];
    const float* wk = (const float*)d_in[1];
    const float* bk = (const float*)d_in[2];
    float* o = (float*)d_out;
    involution_mfma<<<dim3(B_ * G_ * 16), dim3(256), 0, stream>>>(x, wk, bk, o);
}